// Round 13
// baseline (31.843 us; speedup 1.0000x reference)
//
#include <hip/hip_runtime.h>

#define NROWS 8192
#define NCLS  100
#define NB    (NROWS / 4)        // 2048 blocks
#define REP   4                  // probe: rep0 weight 1, reps 1..3 weight 0
#define LN2   0.6931471805599453f
#define LOG2E 1.4426950408889634f

#if __has_builtin(__builtin_amdgcn_exp2f)
#define EXP2F(x) __builtin_amdgcn_exp2f(x)
#else
#define EXP2F(x) __expf((x) * LN2)
#endif
#if __has_builtin(__builtin_amdgcn_logf)
#define LOG2F(x) __builtin_amdgcn_logf(x)
#else
#define LOG2F(x) (__logf(x) * LOG2E)
#endif

// idx in [0,300) -> strict-upper-triangle 4x4 tile coords (I < J), J in [1,25)
#define TILEIJ(idx, I, J) \
    float s_##I = sqrtf(fmaf(8.f, (float)(idx), 1.f)); \
    int J = (int)((1.0f + s_##I) * 0.5f); \
    int I = (idx) - ((J * (J - 1)) >> 1);

// one pair term: P *= (Ea*Rb + Eb*Ra) = 2^-4*(2^(d/2)+2^(-d/2)); f(|d|)=2*log2(h)+8
#define HT(EA, RA, EB, RB, P) { P *= fmaf((EB), (RA), (EA) * (RB)); }

#define TILE16H(Ea, Ra, Eb, Rb, P0, P1, P2, P3) \
  HT(Ea.x, Ra.x, Eb.x, Rb.x, P0) HT(Ea.x, Ra.x, Eb.y, Rb.y, P0) \
  HT(Ea.x, Ra.x, Eb.z, Rb.z, P0) HT(Ea.x, Ra.x, Eb.w, Rb.w, P0) \
  HT(Ea.y, Ra.y, Eb.x, Rb.x, P1) HT(Ea.y, Ra.y, Eb.y, Rb.y, P1) \
  HT(Ea.y, Ra.y, Eb.z, Rb.z, P1) HT(Ea.y, Ra.y, Eb.w, Rb.w, P1) \
  HT(Ea.z, Ra.z, Eb.x, Rb.x, P2) HT(Ea.z, Ra.z, Eb.y, Rb.y, P2) \
  HT(Ea.z, Ra.z, Eb.z, Rb.z, P2) HT(Ea.z, Ra.z, Eb.w, Rb.w, P2) \
  HT(Ea.w, Ra.w, Eb.x, Rb.x, P3) HT(Ea.w, Ra.w, Eb.y, Rb.y, P3) \
  HT(Ea.w, Ra.w, Eb.z, Rb.z, P3) HT(Ea.w, Ra.w, Eb.w, Rb.w, P3)

__global__ __launch_bounds__(256, 8) void cpc_rows_probe(const float* __restrict__ in,
                                                         const int* __restrict__ tgt,
                                                         float* __restrict__ qb) {
    __shared__ __align__(16) float sx[4][128], sE[4][128], sR[4][128];
    __shared__ float bred[4][3];

    const int tid = threadIdx.x;
    const int w   = tid >> 6;                    // wave = row-in-block
    const int l   = tid & 63;
    const int row = blockIdx.x * 4 + w;
    const float* x = in + row * NCLS;

    // ---- stage (x', E, R), log2 domain (R9-identical) ----
    {
        float x0 = x[l] * LOG2E;
        sx[w][l] = x0;
        sE[w][l] = EXP2F((x0 - 4.f) * 0.5f);
        sR[w][l] = EXP2F((x0 + 4.f) * -0.5f);
        if (l < NCLS - 64) {
            float x1 = x[64 + l] * LOG2E;
            sx[w][64 + l] = x1;
            sE[w][64 + l] = EXP2F((x1 - 4.f) * 0.5f);
            sR[w][64 + l] = EXP2F((x1 + 4.f) * -0.5f);
        }
    }
    __syncthreads();

    const int  t  = tgt[row];
    const bool v1 = (l < NCLS - 64);

    float q0a = 0.f, q1a = 0.f, q2a = 0.f;

#pragma unroll 1
    for (int rep = 0; rep < REP; ++rep) {
        // opaque offset (always 0) defeats cross-rep CSE/hoisting of LDS reads & enum
        int off0 = 0;
        asm volatile("" : "+v"(off0));
        const float* px = sx[w] + off0;
        const float* pE = sE[w] + off0;
        const float* pR = sR[w] + off0;

        float x0r = px[l];
        float x1r = v1 ? px[64 + l] : 0.f;
        const float xt = px[t];

        // ---- singles ----
        float At, Pb, es, xs;
        {
            float a0 = fabsf(xt - x0r);
            float e0 = (l == t) ? 0.f : EXP2F(-a0);
            At = a0; Pb = 1.f + e0;
            float E0 = pE[l];
            es = E0 * E0;
            xs = x0r;
        }
        {
            float a1 = v1 ? fabsf(xt - x1r) : 0.f;
            float e1 = (v1 && (64 + l) != t) ? EXP2F(-fabsf(xt - x1r)) : 0.f;
            At += a1; Pb = fmaf(Pb, e1, Pb);
            float E1 = v1 ? pE[64 + l] : 0.f;
            es = v1 ? fmaf(E1, E1, es) : es;
            xs += x1r;
        }
        float lPb = LOG2F(Pb);

        // ---- off-diagonal 4x4 tiles ----
        float P0 = 1.f, P1 = 1.f, P2 = 1.f, P3 = 1.f;
        float cst = 512.f;
#pragma unroll 1
        for (int it = 0; it < 4; ++it) {
            int idx = it * 64 + l + off0;
            TILEIJ(idx, I, J)
            float4 Ea = *(const float4*)(pE + 4 * I);
            float4 Ra = *(const float4*)(pR + 4 * I);
            float4 Eb = *(const float4*)(pE + 4 * J);
            float4 Rb = *(const float4*)(pR + 4 * J);
            TILE16H(Ea, Ra, Eb, Rb, P0, P1, P2, P3)
        }
        {   // tail: idx = 256 + l, valid < 300
            bool tv = (256 + l) < 300;
            int idxc = (tv ? 256 + l : 0) + off0;
            TILEIJ(idxc, I, J)
            float4 Ea = *(const float4*)(pE + 4 * I);
            float4 Ra = *(const float4*)(pR + 4 * I);
            float4 Eb = *(const float4*)(pE + 4 * J);
            float4 Rb = *(const float4*)(pR + 4 * J);
            float S0 = P0, S1 = P1, S2 = P2, S3 = P3;
            TILE16H(Ea, Ra, Eb, Rb, P0, P1, P2, P3)
            P0 = tv ? P0 : S0; P1 = tv ? P1 : S1;
            P2 = tv ? P2 : S2; P3 = tv ? P3 : S3;
            cst += tv ? 128.f : 0.f;
        }
        // ---- diagonal tiles ----
        float Pd0 = 1.f, Pd1 = 1.f;
        {
            bool dv = l < 25;
            int I = (dv ? l : 0) + off0;
            float4 Ea = *(const float4*)(pE + 4 * I);
            float4 Ra = *(const float4*)(pR + 4 * I);
            TILE16H(Ea, Ra, Ea, Ra, Pd0, Pd1, Pd0, Pd1)
            Pd0 = dv ? Pd0 : 1.f;
            Pd1 = dv ? Pd1 : 1.f;
            cst += dv ? 64.f : 0.f;
        }

        float lS = 2.f * ((LOG2F(P0) + LOG2F(P1)) + (LOG2F(P2) + LOG2F(P3)))
                 + LOG2F(Pd0 * Pd1) + cst;

        // ---- packed reduce ----
        float r0 = es;
        float rU = xs + At + 2.f * lPb;
        float rW = At + 2.f * lPb - lS;
#pragma unroll
        for (int off = 32; off; off >>= 1) {
            r0 += __shfl_xor(r0, off, 64);
            rU += __shfl_xor(rU, off, 64);
            rW += __shfl_xor(rW, off, 64);
        }

        float wgt = (rep == 0) ? 1.f : 0.f;      // runtime rep -> not foldable
        q0a += wgt * (LN2 * (LOG2F(r0) + 4.f - xt));
        q1a += wgt * (LN2 * (50.f * xt - 0.5f * rU));
        q2a += wgt * (LN2 * (rW + 1.f));
    }

    if (l == 0) { bred[w][0] = q0a; bred[w][1] = q1a; bred[w][2] = q2a; }
    __syncthreads();
    if (tid < 3) {                               // 3 block-partials, SoA [3][NB]
        float s = bred[0][tid] + bred[1][tid] + bred[2][tid] + bred[3][tid];
        qb[tid * NB + blockIdx.x] = s;
    }
}

__global__ __launch_bounds__(256) void cpc_final(const float* __restrict__ qb,
                                                 float* __restrict__ out) {
    __shared__ double sred[4][3];
    const int tid = threadIdx.x;
    const int lane = tid & 63, wid = tid >> 6;
    double a0 = 0, a1 = 0, a2 = 0;
#pragma unroll
    for (int it = 0; it < 2; ++it) {             // 2 x 256 x 4 = 2048 per comp
        int idx = (it * 256 + tid) * 4;
        float4 v0 = *(const float4*)(qb + idx);
        float4 v1 = *(const float4*)(qb + NB + idx);
        float4 v2 = *(const float4*)(qb + 2 * NB + idx);
        a0 += (double)v0.x; a0 += (double)v0.y; a0 += (double)v0.z; a0 += (double)v0.w;
        a1 += (double)v1.x; a1 += (double)v1.y; a1 += (double)v1.z; a1 += (double)v1.w;
        a2 += (double)v2.x; a2 += (double)v2.y; a2 += (double)v2.z; a2 += (double)v2.w;
    }
#pragma unroll
    for (int off = 32; off; off >>= 1) {
        a0 += __shfl_xor(a0, off, 64);
        a1 += __shfl_xor(a1, off, 64);
        a2 += __shfl_xor(a2, off, 64);
    }
    if (lane == 0) { sred[wid][0] = a0; sred[wid][1] = a1; sred[wid][2] = a2; }
    __syncthreads();
    if (tid == 0) {
        double ce  = (sred[0][0] + sred[1][0] + sred[2][0] + sred[3][0]) / (double)NROWS;
        double bdc = -(sred[0][1] + sred[1][1] + sred[2][1] + sred[3][1])
                     / (double)(NCLS - 1) / (double)NROWS;
        double bec = -0.5 * (sred[0][2] + sred[1][2] + sred[2][2] + sred[3][2])
                     / (double)(NCLS - 1) / (double)(NCLS - 2) / (double)NROWS;
        out[0] = (float)(ce + bdc + bec);
        out[1] = (float)ce;
        out[2] = (float)bdc;
        out[3] = (float)bec;
    }
}

extern "C" void kernel_launch(void* const* d_in, const int* in_sizes, int n_in,
                              void* d_out, int out_size, void* d_ws, size_t ws_size,
                              hipStream_t stream) {
    const float* inputs  = (const float*)d_in[0];
    const int*   targets = (const int*)d_in[1];
    float*       out     = (float*)d_out;
    float*       qb      = (float*)d_ws;         // [3][2048] f32 = 24 KB

    cpc_rows_probe<<<NB, 256, 0, stream>>>(inputs, targets, qb);
    cpc_final<<<1, 256, 0, stream>>>(qb, out);
}

// Round 14
// 14.584 us; speedup vs baseline: 2.1835x; 2.1835x over previous
//
#include <hip/hip_runtime.h>

#define NROWS 8192
#define NCLS  100
#define NB    (NROWS / 4)        // 2048 blocks
#define LN2   0.6931471805599453f
#define LOG2E 1.4426950408889634f

#if __has_builtin(__builtin_amdgcn_exp2f)
#define EXP2F(x) __builtin_amdgcn_exp2f(x)
#else
#define EXP2F(x) __expf((x) * LN2)
#endif
#if __has_builtin(__builtin_amdgcn_logf)
#define LOG2F(x) __builtin_amdgcn_logf(x)
#else
#define LOG2F(x) (__logf(x) * LOG2E)
#endif

// idx in [0,300) -> strict-upper-triangle 4x4 tile coords (I < J), J in [1,25)
#define TILEIJ(idx, I, J) \
    float s_##I = sqrtf(fmaf(8.f, (float)(idx), 1.f)); \
    int J = (int)((1.0f + s_##I) * 0.5f); \
    int I = (idx) - ((J * (J - 1)) >> 1);

// one pair term: P *= (Ea*Rb + Eb*Ra) = 2^-4*(2^(d/2)+2^(-d/2)); f(|d|)=2*log2(h)+8
#define HT(EA, RA, EB, RB, P) { P *= fmaf((EB), (RA), (EA) * (RB)); }

#define TILE16H(Ea, Ra, Eb, Rb, P0, P1, P2, P3) \
  HT(Ea.x, Ra.x, Eb.x, Rb.x, P0) HT(Ea.x, Ra.x, Eb.y, Rb.y, P0) \
  HT(Ea.x, Ra.x, Eb.z, Rb.z, P0) HT(Ea.x, Ra.x, Eb.w, Rb.w, P0) \
  HT(Ea.y, Ra.y, Eb.x, Rb.x, P1) HT(Ea.y, Ra.y, Eb.y, Rb.y, P1) \
  HT(Ea.y, Ra.y, Eb.z, Rb.z, P1) HT(Ea.y, Ra.y, Eb.w, Rb.w, P1) \
  HT(Ea.z, Ra.z, Eb.x, Rb.x, P2) HT(Ea.z, Ra.z, Eb.y, Rb.y, P2) \
  HT(Ea.z, Ra.z, Eb.z, Rb.z, P2) HT(Ea.z, Ra.z, Eb.w, Rb.w, P2) \
  HT(Ea.w, Ra.w, Eb.x, Rb.x, P3) HT(Ea.w, Ra.w, Eb.y, Rb.y, P3) \
  HT(Ea.w, Ra.w, Eb.z, Rb.z, P3) HT(Ea.w, Ra.w, Eb.w, Rb.w, P3)

// wave-64 sum via DPP (VALU pipe only, no LDS): result valid in lane 63
__device__ __forceinline__ float wave_dpp_sum(float v) {
#define DPPADD(ctrl) { int y_ = __builtin_amdgcn_update_dpp( \
        0, __builtin_bit_cast(int, v), (ctrl), 0xf, 0xf, true); \
        v += __builtin_bit_cast(float, y_); }
    DPPADD(0x111)   // row_shr:1
    DPPADD(0x112)   // row_shr:2
    DPPADD(0x114)   // row_shr:4
    DPPADD(0x118)   // row_shr:8  -> lane 15 of each row = row sum
    DPPADD(0x142)   // row_bcast15 -> lane 31 = rows0+1, lane 63 partial
    DPPADD(0x143)   // row_bcast31 -> lane 63 = total
#undef DPPADD
    return v;
}

__global__ __launch_bounds__(256, 8) void cpc_rows(const float* __restrict__ in,
                                                   const int* __restrict__ tgt,
                                                   float* __restrict__ qb) {
    __shared__ __align__(16) float sx[4][128], sE[4][128], sR[4][128];
    __shared__ float bred[4][3];

    const int tid = threadIdx.x;
    const int w   = tid >> 6;                    // wave = row-in-block
    const int l   = tid & 63;
    const int row = blockIdx.x * 4 + w;
    const float* x = in + row * NCLS;

    // ---- stage (x', E, R), log2 domain ----
    float x0 = x[l] * LOG2E;
    float E0 = EXP2F((x0 - 4.f) * 0.5f);
    sx[w][l] = x0;
    sE[w][l] = E0;
    sR[w][l] = EXP2F((x0 + 4.f) * -0.5f);
    const bool v1 = (l < NCLS - 64);             // lanes 0..35 hold a second class
    float x1 = 0.f, E1 = 0.f;
    if (v1) {
        x1 = x[64 + l] * LOG2E;
        E1 = EXP2F((x1 - 4.f) * 0.5f);
        sx[w][64 + l] = x1;
        sE[w][64 + l] = E1;
        sR[w][64 + l] = EXP2F((x1 + 4.f) * -0.5f);
    }
    __syncthreads();

    const int   t  = tgt[row];
    const float xt = sx[w][t];

    // ---- singles: sumexp (via E^2), sum-x, target-pair stats ----
    float At, Pb, es, xs;
    {
        float a0 = fabsf(xt - x0);
        float e0 = (l == t) ? 0.f : EXP2F(-a0);
        At = a0; Pb = 1.f + e0;
        es = E0 * E0;                            // = 2^(x0-4)
        xs = x0;
    }
    {
        float a1 = v1 ? fabsf(xt - x1) : 0.f;
        float e1 = (v1 && (64 + l) != t) ? EXP2F(-a1) : 0.f;
        At += a1; Pb = fmaf(Pb, e1, Pb);
        es = v1 ? fmaf(E1, E1, es) : es;
        xs += x1;                                // x1 = 0 when !v1
    }
    float lPb = LOG2F(Pb);

    const float* pE = sE[w];
    const float* pR = sR[w];

    // ---- off-diagonal 4x4 tiles: 300 tiles; products of h, no trans in loop ----
    float P0 = 1.f, P1 = 1.f, P2 = 1.f, P3 = 1.f;
    float cst = 512.f;                           // 4 iters x 16 terms x 8
#pragma unroll 1
    for (int it = 0; it < 4; ++it) {
        int idx = it * 64 + l;
        TILEIJ(idx, I, J)
        float4 Ea = *(const float4*)(pE + 4 * I);
        float4 Ra = *(const float4*)(pR + 4 * I);
        float4 Eb = *(const float4*)(pE + 4 * J);
        float4 Rb = *(const float4*)(pR + 4 * J);
        TILE16H(Ea, Ra, Eb, Rb, P0, P1, P2, P3)
    }
    {   // tail: idx = 256 + l, valid < 300
        int idx = 256 + l;
        bool tv = idx < 300;
        int idxc = tv ? idx : 0;
        TILEIJ(idxc, I, J)
        float4 Ea = *(const float4*)(pE + 4 * I);
        float4 Ra = *(const float4*)(pR + 4 * I);
        float4 Eb = *(const float4*)(pE + 4 * J);
        float4 Rb = *(const float4*)(pR + 4 * J);
        float S0 = P0, S1 = P1, S2 = P2, S3 = P3;
        TILE16H(Ea, Ra, Eb, Rb, P0, P1, P2, P3)
        P0 = tv ? P0 : S0; P1 = tv ? P1 : S1;
        P2 = tv ? P2 : S2; P3 = tv ? P3 : S3;
        cst += tv ? 128.f : 0.f;
    }
    // ---- diagonal tiles: lane<25 -> tile (l,l); all 16 entries, halved in account ----
    float Pd0 = 1.f, Pd1 = 1.f;
    {
        bool dv = l < 25;
        int I = dv ? l : 0;
        float4 Ea = *(const float4*)(pE + 4 * I);
        float4 Ra = *(const float4*)(pR + 4 * I);
        TILE16H(Ea, Ra, Ea, Ra, Pd0, Pd1, Pd0, Pd1)
        Pd0 = dv ? Pd0 : 1.f;
        Pd1 = dv ? Pd1 : 1.f;
        cst += dv ? 64.f : 0.f;
    }

    // lS = sum of f over assigned pairs (+ halved selfs), log2 units
    float lS = 2.f * ((LOG2F(P0) + LOG2F(P1)) + (LOG2F(P2) + LOG2F(P3)))
             + LOG2F(Pd0 * Pd1) + cst;

    // ---- packed reduce: 3 values, DPP (VALU) — totals land in lane 63 ----
    float r0 = wave_dpp_sum(es);                 // -> sumexp * 2^-4
    float rU = wave_dpp_sum(xs + At + 2.f * lPb);            // -> q1
    float rW = wave_dpp_sum(At + 2.f * lPb - lS);            // -> q2

    if (l == 63) {
        bred[w][0] = LN2 * (LOG2F(r0) + 4.f - xt);     // CE
        bred[w][1] = LN2 * (50.f * xt - 0.5f * rU);    // sum logsig(xt - rest)
        bred[w][2] = LN2 * (rW + 1.f);                 // rest-pairs (+99*logsig(0))
    }
    __syncthreads();
    if (tid < 3) {                               // 3 block-partials, SoA [3][NB]
        float s = bred[0][tid] + bred[1][tid] + bred[2][tid] + bred[3][tid];
        qb[tid * NB + blockIdx.x] = s;
    }
}

__global__ __launch_bounds__(256) void cpc_final(const float* __restrict__ qb,
                                                 float* __restrict__ out) {
    __shared__ double sred[4][3];
    const int tid = threadIdx.x;
    const int lane = tid & 63, wid = tid >> 6;
    double a0 = 0, a1 = 0, a2 = 0;
#pragma unroll
    for (int it = 0; it < 2; ++it) {             // 2 x 256 x 4 = 2048 per comp
        int idx = (it * 256 + tid) * 4;
        float4 v0 = *(const float4*)(qb + idx);
        float4 v1 = *(const float4*)(qb + NB + idx);
        float4 v2 = *(const float4*)(qb + 2 * NB + idx);
        a0 += (double)v0.x; a0 += (double)v0.y; a0 += (double)v0.z; a0 += (double)v0.w;
        a1 += (double)v1.x; a1 += (double)v1.y; a1 += (double)v1.z; a1 += (double)v1.w;
        a2 += (double)v2.x; a2 += (double)v2.y; a2 += (double)v2.z; a2 += (double)v2.w;
    }
#pragma unroll
    for (int off = 32; off; off >>= 1) {
        a0 += __shfl_xor(a0, off, 64);
        a1 += __shfl_xor(a1, off, 64);
        a2 += __shfl_xor(a2, off, 64);
    }
    if (lane == 0) { sred[wid][0] = a0; sred[wid][1] = a1; sred[wid][2] = a2; }
    __syncthreads();
    if (tid == 0) {
        double ce  = (sred[0][0] + sred[1][0] + sred[2][0] + sred[3][0]) / (double)NROWS;
        double bdc = -(sred[0][1] + sred[1][1] + sred[2][1] + sred[3][1])
                     / (double)(NCLS - 1) / (double)NROWS;
        double bec = -0.5 * (sred[0][2] + sred[1][2] + sred[2][2] + sred[3][2])
                     / (double)(NCLS - 1) / (double)(NCLS - 2) / (double)NROWS;
        out[0] = (float)(ce + bdc + bec);
        out[1] = (float)ce;
        out[2] = (float)bdc;
        out[3] = (float)bec;
    }
}

extern "C" void kernel_launch(void* const* d_in, const int* in_sizes, int n_in,
                              void* d_out, int out_size, void* d_ws, size_t ws_size,
                              hipStream_t stream) {
    const float* inputs  = (const float*)d_in[0];
    const int*   targets = (const int*)d_in[1];
    float*       out     = (float*)d_out;
    float*       qb      = (float*)d_ws;         // [3][2048] f32 = 24 KB

    cpc_rows<<<NB, 256, 0, stream>>>(inputs, targets, qb);
    cpc_final<<<1, 256, 0, stream>>>(qb, out);
}